// Round 8
// baseline (305.487 us; speedup 1.0000x reference)
//
#include <hip/hip_runtime.h>
#include <math.h>

#define N 128
#define VOL (N*N*N)            // 2097152
#define PLANE (N*N)            // 16384
#define NKX 65                 // kept x-frequencies 0..64 (Hermitian half)
#define NSHELL 65              // shells 0..64
#define ACC_STRIDE 195         // 3*65 per batch

__device__ __forceinline__ int rev6(int x) { return (int)(__brev((unsigned)x) >> 26); }

__device__ __forceinline__ float2 cmul(float2 a, float2 b) {
    return make_float2(a.x * b.x - a.y * b.y, a.x * b.y + a.y * b.x);
}

// Packed-bf16 lane exchange: complex -> one b32 word -> single shuffle.
__device__ __forceinline__ float2 shflx16(float2 v, int m) {
    unsigned p = __builtin_amdgcn_perm(__float_as_uint(v.y), __float_as_uint(v.x), 0x07060302u);
    unsigned q = (unsigned)__shfl_xor((int)p, m);
    return make_float2(__uint_as_float(q << 16), __uint_as_float(q & 0xFFFF0000u));
}

// bf16x2 pack (RNE) / unpack: complex value in one uint (re low, im high)
__device__ __forceinline__ unsigned int pack_bf2(float2 v) {
    unsigned int r = __float_as_uint(v.x);
    unsigned int i = __float_as_uint(v.y);
    r = (r + 0x7FFFu + ((r >> 16) & 1u)) >> 16;
    i = (i + 0x7FFFu + ((i >> 16) & 1u)) & 0xFFFF0000u;
    return i | r;
}
__device__ __forceinline__ float2 unpack_bf2(unsigned int u) {
    return make_float2(__uint_as_float(u << 16), __uint_as_float(u & 0xFFFF0000u));
}

// fp8 e4m3 packed complex (re byte0, im byte1) for the in-LDS plane
__device__ __forceinline__ unsigned short pack_f8(float2 v) {
    int p = __builtin_amdgcn_cvt_pk_fp8_f32(v.x, v.y, 0, false);
    return (unsigned short)(p & 0xFFFF);
}
__device__ __forceinline__ float2 unpack_f8(unsigned short u) {
    auto r = __builtin_amdgcn_cvt_pk_f32_fp8((int)u, false);
    return make_float2(r[0], r[1]);
}

// 64-entry twiddle table W[m] = e^{-2*pi*i*m/128}, built once per block
__device__ __forceinline__ void build_W(float2* Wsh, int tid) {
    if (tid < 64) {
        float s, c;
        sincosf(-6.283185307179586f * (float)tid / 128.0f, &s, &c);
        Wsh[tid] = make_float2(c, s);
    }
}

// Per-lane effective twiddles (identity on low lanes -> branchless butterfly)
struct TwE { float2 w128; float2 we[5]; };

__device__ __forceinline__ TwE make_twe(const float2* Wsh, int lane) {
    TwE w;
    w.w128 = Wsh[lane];
    #pragma unroll
    for (int i = 0; i < 5; i++) {
        int h = 32 >> i;
        float2 t = Wsh[(lane & (h - 1)) << (i + 1)];
        w.we[i] = (lane & h) ? t : make_float2(1.0f, 0.0f);
    }
    return w;
}

__device__ __forceinline__ void bstage(float2& v, float2 o, float s, float2 we) {
    float tx = fmaf(s, v.x, o.x);
    float ty = fmaf(s, v.y, o.y);
    v = make_float2(tx * we.x - ty * we.y, tx * we.y + ty * we.x);
}

// Two independent 128-pt DIF FFTs, interleaved; packed-bf16 exchanges.
// Output: a0 = X[2*rev6(lane)], a1 = X[2*rev6(lane)+1].
__device__ __forceinline__ void fft128x2(float2& a0, float2& a1,
                                         float2& b0, float2& b1,
                                         const TwE& w, int lane) {
    float2 d;
    d  = make_float2(a0.x - a1.x, a0.y - a1.y);
    a0 = make_float2(a0.x + a1.x, a0.y + a1.y);
    a1 = cmul(d, w.w128);
    d  = make_float2(b0.x - b1.x, b0.y - b1.y);
    b0 = make_float2(b0.x + b1.x, b0.y + b1.y);
    b1 = cmul(d, w.w128);
    #pragma unroll
    for (int i = 0; i < 5; i++) {
        int h = 32 >> i;
        float s = (lane & h) ? -1.0f : 1.0f;
        float2 oa0 = shflx16(a0, h);
        float2 oa1 = shflx16(a1, h);
        float2 ob0 = shflx16(b0, h);
        float2 ob1 = shflx16(b1, h);
        bstage(a0, oa0, s, w.we[i]);
        bstage(a1, oa1, s, w.we[i]);
        bstage(b0, ob0, s, w.we[i]);
        bstage(b1, ob1, s, w.we[i]);
    }
    float s = (lane & 1) ? -1.0f : 1.0f;
    float2 oa0 = shflx16(a0, 1);
    float2 oa1 = shflx16(a1, 1);
    float2 ob0 = shflx16(b0, 1);
    float2 ob1 = shflx16(b1, 1);
    a0 = make_float2(fmaf(s, a0.x, oa0.x), fmaf(s, a0.y, oa0.y));
    a1 = make_float2(fmaf(s, a1.x, oa1.x), fmaf(s, a1.y, oa1.y));
    b0 = make_float2(fmaf(s, b0.x, ob0.x), fmaf(s, b0.y, ob0.y));
    b1 = make_float2(fmaf(s, b1.x, ob1.x), fmaf(s, b1.y, ob1.y));
}

// slot index holding frequency k after fft128
__device__ __forceinline__ int slot_of(int k) {
    return (k & 1) ? 64 + rev6(k >> 1) : rev6(k >> 1);
}

// ---- Pass 1: packed x-FFT (L = mo + i*tg), Hermitian unpack, keep kx=0..64 ----
// grid: nb*128(z)*8(ytile) blocks of 256. Output (bf16x2): [vol][b][kx][z][y].
// All 16 global loads per wave are issued before any FFT (max MLP).
__global__ __launch_bounds__(256, 8)
void fft_x_pack_kernel(const float* __restrict__ in0, const float* __restrict__ in1,
                       unsigned int* __restrict__ wso, unsigned int* __restrict__ wst,
                       int b0, float scale)
{
    __shared__ float2 tile[16][129];
    __shared__ float2 Wsh[64];
    int tid = threadIdx.x, lane = tid & 63, wave = tid >> 6;
    int bi = blockIdx.x;
    int yt = bi & 7, z = (bi >> 3) & 127, b = bi >> 10;
    build_W(Wsh, tid);

    size_t src_base = (size_t)(b0 + b) * VOL + (size_t)z * PLANE + (size_t)(yt * 16 + wave * 4) * N;
    const float* q0 = in0 + src_base;
    const float* q1 = in1 + src_base;
    // issue all 16 loads up-front
    float m0a = q0[lane],           m0b = q0[lane + 64];
    float t0a = q1[lane],           t0b = q1[lane + 64];
    float m1a = q0[N + lane],       m1b = q0[N + lane + 64];
    float t1a = q1[N + lane],       t1b = q1[N + lane + 64];
    float m2a = q0[2*N + lane],     m2b = q0[2*N + lane + 64];
    float t2a = q1[2*N + lane],     t2b = q1[2*N + lane + 64];
    float m3a = q0[3*N + lane],     m3b = q0[3*N + lane + 64];
    float t3a = q1[3*N + lane],     t3b = q1[3*N + lane + 64];
    __syncthreads();
    TwE w = make_twe(Wsh, lane);

    int j0 = wave * 4;
    {
        float2 a0 = make_float2(m0a * scale, t0a * scale);
        float2 a1 = make_float2(m0b * scale, t0b * scale);
        float2 c0 = make_float2(m1a * scale, t1a * scale);
        float2 c1 = make_float2(m1b * scale, t1b * scale);
        fft128x2(a0, a1, c0, c1, w, lane);
        tile[j0][lane]          = a0;
        tile[j0][lane + 64]     = a1;
        tile[j0 + 1][lane]      = c0;
        tile[j0 + 1][lane + 64] = c1;
    }
    {
        float2 a0 = make_float2(m2a * scale, t2a * scale);
        float2 a1 = make_float2(m2b * scale, t2b * scale);
        float2 c0 = make_float2(m3a * scale, t3a * scale);
        float2 c1 = make_float2(m3b * scale, t3b * scale);
        fft128x2(a0, a1, c0, c1, w, lane);
        tile[j0 + 2][lane]      = a0;
        tile[j0 + 2][lane + 64] = a1;
        tile[j0 + 3][lane]      = c0;
        tile[j0 + 3][lane + 64] = c1;
    }
    __syncthreads();

    // unpack both O and T from the same LDS pair (1040 iterations, shared reads)
    size_t dst_off = (size_t)b * NKX * PLANE + (size_t)z * N + yt * 16;
    for (int idx = tid; idx < NKX * 16; idx += 256) {
        int j  = idx & 15;
        int kx = idx >> 4;               // 0..64
        int mk = (128 - kx) & 127;
        float2 a  = tile[j][slot_of(kx)];
        float2 bm = tile[j][slot_of(mk)];
        float2 o = make_float2(0.5f * (a.x + bm.x), 0.5f * (a.y - bm.y));
        float2 t = make_float2(0.5f * (a.y + bm.y), 0.5f * (bm.x - a.x));
        size_t off = dst_off + (size_t)kx * PLANE + j;
        wso[off] = pack_bf2(o);
        wst[off] = pack_bf2(t);
    }
}

// ---- Fused pass 2: y-FFT + z-FFT + shell accumulation per (b, kx) plane ----
// grid: nb*65 blocks of 1024 (16 waves). LDS plane as fp8x2.
// Swizzle col = (z + ky) & 127. Phase A/B software-pipelined (prefetch depth 1).
__global__ __launch_bounds__(1024, 8)
void fft_yz_acc_kernel(const unsigned int* __restrict__ wsv, float* __restrict__ gacc,
                       int nb, int b0)
{
    __shared__ unsigned short tile[2][128][128];   // 65536 B
    __shared__ float2 Wsh[64];
    __shared__ float accn[NSHELL], accp[NSHELL], accq[NSHELL];
    int tid = threadIdx.x, lane = tid & 63, wave = tid >> 6;
    int bi = blockIdx.x;
    int kx = bi % NKX, b = bi / NKX;
    build_W(Wsh, tid);
    if (tid >= 64 && tid < 64 + NSHELL) {
        int s0 = tid - 64;
        accn[s0] = 0.0f; accp[s0] = 0.0f; accq[s0] = 0.0f;
    }
    __syncthreads();
    TwE w = make_twe(Wsh, lane);

    // Phase A: 256 y-FFT lines. vol = wave>>3 is wave-uniform; wave handles
    // z = (wave&7)*16 .. +15, in pairs, with next-pair global loads in flight.
    int nv = nb * NKX;
    int vol = wave >> 3;
    const unsigned int* pb = wsv + ((size_t)vol * nv + (size_t)b * NKX + kx) * PLANE
                                 + (size_t)((wave & 7) * 16) * N;
    unsigned u0 = pb[lane], u1 = pb[lane + 64], u2 = pb[N + lane], u3 = pb[N + lane + 64];
    #pragma unroll
    for (int c = 0; c < 16; c += 2) {
        unsigned n0 = 0, n1 = 0, n2 = 0, n3 = 0;
        if (c + 2 < 16) {
            const unsigned int* q = pb + (size_t)(c + 2) * N;
            n0 = q[lane]; n1 = q[lane + 64]; n2 = q[N + lane]; n3 = q[N + lane + 64];
        }
        float2 a0 = unpack_bf2(u0);
        float2 a1 = unpack_bf2(u1);
        float2 c0 = unpack_bf2(u2);
        float2 c1 = unpack_bf2(u3);
        fft128x2(a0, a1, c0, c1, w, lane);
        int z0 = (wave & 7) * 16 + c, z1 = z0 + 1;
        int ky0 = 2 * rev6(lane);                // a1/c1 hold ky0+1
        tile[vol][ky0][(z0 + ky0) & 127]         = pack_f8(a0);
        tile[vol][ky0 + 1][(z0 + ky0 + 1) & 127] = pack_f8(a1);
        tile[vol][ky0][(z1 + ky0) & 127]         = pack_f8(c0);
        tile[vol][ky0 + 1][(z1 + ky0 + 1) & 127] = pack_f8(c1);
        u0 = n0; u1 = n1; u2 = n2; u3 = n3;
    }
    __syncthreads();

    // Phase B: z-FFT per live ky line (o and t interleaved) + accumulate,
    // with next iteration's LDS reads prefetched unconditionally.
    int kx2 = kx * kx;
    int kz0 = 2 * rev6(lane), kz1 = kz0 + 1;
    int cz0 = (kz0 < 64) ? kz0 : kz0 - 128;
    int cz1 = (kz1 < 64) ? kz1 : kz1 - 128;
    int z20 = cz0 * cz0, z21 = cz1 * cz1;

    int ky = wave;
    int rc0 = (lane + ky) & 127, rc1 = (lane + 64 + ky) & 127;
    unsigned short qo0 = tile[0][ky][rc0], qo1 = tile[0][ky][rc1];
    unsigned short qt0 = tile[1][ky][rc0], qt1 = tile[1][ky][rc1];
    #pragma unroll
    for (int c = 0; c < 8; c++) {
        unsigned short po0 = 0, po1 = 0, pt0 = 0, pt1 = 0;
        if (c < 7) {
            int kyn = ky + 16;
            int nc0 = (lane + kyn) & 127, nc1 = (lane + 64 + kyn) & 127;
            po0 = tile[0][kyn][nc0]; po1 = tile[0][kyn][nc1];
            pt0 = tile[1][kyn][nc0]; pt1 = tile[1][kyn][nc1];
        }
        int cy = (ky < 64) ? ky : ky - 128;
        int base2 = kx2 + cy * cy;
        if (base2 <= 4224) {
            float2 o0 = unpack_f8(qo0);
            float2 o1 = unpack_f8(qo1);
            float2 t0 = unpack_f8(qt0);
            float2 t1 = unpack_f8(qt1);
            fft128x2(o0, o1, t0, t1, w, lane);
            int r20 = base2 + z20;
            if (r20 <= 4224) {
                int sh = (int)sqrtf((float)r20);
                if ((sh + 1) * (sh + 1) <= r20) sh++;
                else if (sh * sh > r20) sh--;
                atomicAdd(&accn[sh], o0.x * t0.x + o0.y * t0.y);
                atomicAdd(&accp[sh], o0.x * o0.x + o0.y * o0.y);
                atomicAdd(&accq[sh], t0.x * t0.x + t0.y * t0.y);
            }
            int r21 = base2 + z21;
            if (r21 <= 4224) {
                int sh = (int)sqrtf((float)r21);
                if ((sh + 1) * (sh + 1) <= r21) sh++;
                else if (sh * sh > r21) sh--;
                atomicAdd(&accn[sh], o1.x * t1.x + o1.y * t1.y);
                atomicAdd(&accp[sh], o1.x * o1.x + o1.y * o1.y);
                atomicAdd(&accq[sh], t1.x * t1.x + t1.y * t1.y);
            }
        }
        ky += 16;
        qo0 = po0; qo1 = po1; qt0 = pt0; qt1 = pt1;
    }
    __syncthreads();

    if (tid < NSHELL) {
        // Hermitian mirror weight * 1/256 (undo the ×16 amplitude pre-scale)
        float wgt = ((kx == 0 || kx == 64) ? 1.0f : 2.0f) * (1.0f / 256.0f);
        float* g = gacc + (size_t)(b0 + b) * ACC_STRIDE;
        atomicAdd(&g[tid],              wgt * accn[tid]);
        atomicAdd(&g[NSHELL + tid],     wgt * accp[tid]);
        atomicAdd(&g[2 * NSHELL + tid], wgt * accq[tid]);
    }
}

// ---------------- Finalize: fsc -> loss scalar -----------------------------
__global__ void finalize_kernel(const float* __restrict__ gacc,
                                float* __restrict__ out)
{
    int lane = threadIdx.x;   // 64 threads, shell = lane+1 (1..64)
    int sh = lane + 1;
    float total = 0.0f;
    #pragma unroll
    for (int b = 0; b < 8; b++) {
        const float* g = gacc + b * ACC_STRIDE;
        float num = g[sh];
        float po  = g[NSHELL + sh];
        float pt  = g[2 * NSHELL + sh];
        float fsc = num / sqrtf(po * pt + 1e-6f);
        fsc = fminf(1.0f, fmaxf(-1.0f, fsc));
        total += fsc;
    }
    #pragma unroll
    for (int off = 32; off; off >>= 1) total += __shfl_down(total, off);
    if (lane == 0) out[0] = 1.0f - total / (64.0f * 8.0f);
}

extern "C" void kernel_launch(void* const* d_in, const int* in_sizes, int n_in,
                              void* d_out, int out_size, void* d_ws, size_t ws_size,
                              hipStream_t stream) {
    const float* in0 = (const float*)d_in[0];   // model_output (8,1,128,128,128)
    const float* in1 = (const float*)d_in[1];   // target
    float* gacc = (float*)d_ws;                 // 8*195 floats
    unsigned int* wsA = (unsigned int*)((char*)d_ws + 8192);

    hipMemsetAsync(d_ws, 0, 8 * ACC_STRIDE * sizeof(float), stream);

    size_t avail = (ws_size > 8192) ? ws_size - 8192 : 0;
    size_t per_batch = 2ull * NKX * PLANE * sizeof(unsigned int);   // ~8.5 MB
    int NB = (int)(avail / per_batch);
    if (NB > 8) NB = 8;
    if (NB < 1) NB = 1;

    // 16 / sqrt(128^3): ortho norm plus ×16 amplitude pre-scale so the fp8
    // LDS plane sits in e4m3's sweet spot; shell sums are ×256, undone at flush.
    const float scale = 1.1048543456039804e-2f;

    for (int b0 = 0; b0 < 8; b0 += NB) {
        int nb = (8 - b0 < NB) ? (8 - b0) : NB;
        size_t plane_cnt = (size_t)nb * NKX * PLANE;
        unsigned int* wso = wsA;                 // [vol][b][kx][z][y] bf16x2
        unsigned int* wst = wsA + plane_cnt;
        fft_x_pack_kernel<<<dim3(nb * 1024), dim3(256), 0, stream>>>(in0, in1, wso, wst, b0, scale);
        fft_yz_acc_kernel<<<dim3(nb * NKX), dim3(1024), 0, stream>>>(wsA, gacc, nb, b0);
    }
    finalize_kernel<<<dim3(1), dim3(64), 0, stream>>>(gacc, (float*)d_out);
}